// Round 1
// 385.634 us; speedup vs baseline: 1.0501x; 1.0501x over previous
//
#include <hip/hip_runtime.h>

typedef unsigned short u16;
typedef float f32x4 __attribute__((ext_vector_type(4)));
typedef __bf16 bf16x8 __attribute__((ext_vector_type(8)));

// ---------- bf16 helpers (RNE) ----------
__device__ __forceinline__ u16 f2bf(float f) {
    unsigned u = __float_as_uint(f);
    u += 0x7FFFu + ((u >> 16) & 1u);
    return (u16)(u >> 16);
}
__device__ __forceinline__ float b2f(u16 h) {
    return __uint_as_float(((unsigned)h) << 16);
}

// ---------- async global->LDS, 16B per lane, wave-uniform LDS base ----------
__device__ __forceinline__ void async16(const u16* g, u16* l) {
    __builtin_amdgcn_global_load_lds(
        (__attribute__((address_space(1))) void*)(u16*)g,
        (__attribute__((address_space(3))) void*)l,
        16, 0, 0);
}

#define T_TOK 4096
#define DIM   2048

// ---------- fused: W_in cast (blocks 0..8191) + LayerNorm (blocks 8192..12287) ----------
__global__ __launch_bounds__(256) void castln_kernel(const float* __restrict__ W_in,
                                                     u16* __restrict__ wb_in,
                                                     const float* __restrict__ x,
                                                     const float* __restrict__ g,
                                                     const float* __restrict__ b,
                                                     u16* __restrict__ o) {
    __shared__ float s1[4], s2[4];
    int blk = blockIdx.x, tid = threadIdx.x;
    if (blk < 8192) {               // cast path: 2,097,152 float4s
        int i = blk * 256 + tid;
        float4 f = ((const float4*)W_in)[i];
        ushort4 u;
        u.x = f2bf(f.x); u.y = f2bf(f.y); u.z = f2bf(f.z); u.w = f2bf(f.w);
        ((ushort4*)wb_in)[i] = u;
        return;
    }
    int t = blk - 8192;
    int wave = tid >> 6, lane = tid & 63;
    size_t base = (size_t)t * DIM;
    int d0 = tid * 8;
    float4 v0 = *(const float4*)(x + base + d0);
    float4 v1 = *(const float4*)(x + base + d0 + 4);
    float v[8] = {v0.x, v0.y, v0.z, v0.w, v1.x, v1.y, v1.z, v1.w};
    float s = 0.f;
#pragma unroll
    for (int j = 0; j < 8; ++j) s += v[j];
#pragma unroll
    for (int o2 = 32; o2; o2 >>= 1) s += __shfl_xor(s, o2);
    if (lane == 0) s1[wave] = s;
    __syncthreads();
    float mu = (s1[0] + s1[1] + s1[2] + s1[3]) * (1.f / DIM);
    float q = 0.f;
#pragma unroll
    for (int j = 0; j < 8; ++j) { float dd = v[j] - mu; q += dd * dd; }
#pragma unroll
    for (int o2 = 32; o2; o2 >>= 1) q += __shfl_xor(q, o2);
    if (lane == 0) s2[wave] = q;
    __syncthreads();
    float var = (s2[0] + s2[1] + s2[2] + s2[3]) * (1.f / DIM);
    float rs = rsqrtf(var + 1e-5f);
    float4 g0 = *(const float4*)(g + d0), g1 = *(const float4*)(g + d0 + 4);
    float4 b0 = *(const float4*)(b + d0), b1 = *(const float4*)(b + d0 + 4);
    float gv[8] = {g0.x, g0.y, g0.z, g0.w, g1.x, g1.y, g1.z, g1.w};
    float bv[8] = {b0.x, b0.y, b0.z, b0.w, b1.x, b1.y, b1.z, b1.w};
    ushort4 r0, r1;
    u16* rp0 = (u16*)&r0; u16* rp1 = (u16*)&r1;
#pragma unroll
    for (int j = 0; j < 4; ++j) {
        rp0[j] = f2bf((v[j] - mu) * rs * gv[j] + bv[j]);
        rp1[j] = f2bf((v[j + 4] - mu) * rs * gv[j + 4] + bv[j + 4]);
    }
    *(ushort4*)(o + base + d0) = r0;
    *(ushort4*)(o + base + d0 + 4) = r1;
}

// ---------- 4-range weight cast (W_dt, W_B, W_C, W_out in one launch) ----------
__global__ __launch_bounds__(256) void cast4_kernel(const float* __restrict__ s0, u16* __restrict__ d0, int n0,
                                                    const float* __restrict__ s1, u16* __restrict__ d1, int n1,
                                                    const float* __restrict__ s2, u16* __restrict__ d2, int n2,
                                                    const float* __restrict__ s3, u16* __restrict__ d3, int n3) {
    int j = blockIdx.x * 256 + threadIdx.x;
    const float* s; u16* d;
    if (j < n0) { s = s0; d = d0; }
    else {
        j -= n0;
        if (j < n1) { s = s1; d = d1; }
        else {
            j -= n1;
            if (j < n2) { s = s2; d = d2; }
            else { j -= n2; if (j >= n3) return; s = s3; d = d3; }
        }
    }
    float4 f = ((const float4*)s)[j];
    ushort4 u;
    u.x = f2bf(f.x); u.y = f2bf(f.y); u.z = f2bf(f.z); u.w = f2bf(f.w);
    ((ushort4*)d)[j] = u;
}

// ---------- wide GEMM: 256x256 tile, BK=64, 8-wave, 8-phase counted-vmcnt ----------
// m201-template port. 512 threads = 8 waves (2M x 4N); per-wave output 128x64.
// LDS 128 KiB: lA[2][256x64] + lB[2][256x64] bf16, double-buffered.
// Iteration = 2 K-tiles, 8 phases; phase = {ds_read frags | stage issue} ->
// sched_barrier+s_barrier -> setprio(1) 16 MFMA setprio(0) -> [vmcnt(4) at
// ph4/ph8 only] -> sched_barrier+s_barrier. vmcnt is never drained to 0 in the
// loop: 4 loads (one matrix-tile) stay in flight across each wait.
// Stage schedule (iter i; buf0=kt2i, buf1=kt2i+1):
//   ph1: B1<-2i+1 (prev read ended iter i-1 ph8)   needed ph5, wait ph4
//   ph4: A0<-2i+2 (buf0 A last read ph3)           needed next ph1, wait ph8
//   ph5: B0<-2i+2 (buf0 B last read ph4)           needed next ph1, wait ph8
//   ph8: A1<-2i+3 (buf1 A last read ph7)           needed next ph5, wait next ph4
// XOR swizzle (proven, 0 conflicts): chunk c of row R lives at slot c ^ (R&7);
// staging pre-swizzles the GLOBAL source column, LDS dest stays linear.
#define GBM 256
#define GBN 256
#define GBK 64

#define WAITV4 asm volatile("s_waitcnt vmcnt(4)" ::: "memory")
#define SBAR() do { __builtin_amdgcn_sched_barrier(0); __builtin_amdgcn_s_barrier(); } while (0)

__global__ __launch_bounds__(512) void gemm_wide(const u16* __restrict__ A,
                                                 const u16* __restrict__ W,
                                                 const float* __restrict__ bias,
                                                 u16* __restrict__ Xs,
                                                 u16* __restrict__ Z, int K) {
    __shared__ __align__(16) u16 lA[2][GBM * GBK];   // 64 KB
    __shared__ __align__(16) u16 lB[2][GBN * GBK];   // 64 KB
    const int tid = threadIdx.x;
    const int wv = tid >> 6, lane = tid & 63;
    const int quad = lane >> 4, l16 = lane & 15;
    const int wr = wv >> 2, wc = wv & 3;               // 2 x 4 wave grid
    const int tM = blockIdx.x * GBM, tN = blockIdx.y * GBN;

    // staging: 512 threads x 16B = 8 KB/round = 64 rows; 4 rounds per tile.
    const int srow = tid >> 3;                          // 0..63
    const int swz = ((tid & 7) ^ (srow & 7)) * 8;       // pre-swizzled src chunk
    const u16* gA = A + (size_t)(tM + srow) * 2048 + swz;
    const u16* gW = W + (size_t)(tN + srow) * 2048 + swz;

#define STAGE_A(BI, KC) do {                                                  \
    _Pragma("unroll") for (int r_ = 0; r_ < 4; ++r_)                          \
      async16(gA + (size_t)r_ * 64 * 2048 + (KC),                             \
              &lA[BI][(r_ * 64 + wv * 8) * GBK]);                             \
  } while (0)
#define STAGE_B(BI, KC) do {                                                  \
    _Pragma("unroll") for (int r_ = 0; r_ < 4; ++r_)                          \
      async16(gW + (size_t)r_ * 64 * 2048 + (KC),                             \
              &lB[BI][(r_ * 64 + wv * 8) * GBK]);                             \
  } while (0)

    // ds_read offsets (elements). Read of global k-chunk g at row R uses LDS
    // slot g ^ (R&7); R&7 == l16&7 here.
    int aoff[2][4][2], boff[2][2][2];
#pragma unroll
    for (int qm = 0; qm < 2; ++qm)
#pragma unroll
        for (int mi = 0; mi < 4; ++mi)
#pragma unroll
            for (int h = 0; h < 2; ++h) {
                int row = wr * 128 + (qm * 4 + mi) * 16 + l16;
                aoff[qm][mi][h] = row * GBK + (((h * 4 + quad) ^ (l16 & 7)) * 8);
            }
#pragma unroll
    for (int qn = 0; qn < 2; ++qn)
#pragma unroll
        for (int ni = 0; ni < 2; ++ni)
#pragma unroll
            for (int h = 0; h < 2; ++h) {
                int row = wc * 64 + (qn * 2 + ni) * 16 + l16;
                boff[qn][ni][h] = row * GBK + (((h * 4 + quad) ^ (l16 & 7)) * 8);
            }

    f32x4 acc[8][4] = {};
    bf16x8 af[4][2];   // A frags persist across the two phases of a qm-half

#define PHASE(BI, QM, QN, LOADA, STAGE_STMT, WAIT_STMT) do {                  \
    if (LOADA) {                                                              \
      _Pragma("unroll") for (int mi_ = 0; mi_ < 4; ++mi_)                     \
        _Pragma("unroll") for (int h_ = 0; h_ < 2; ++h_)                      \
          af[mi_][h_] = *(const bf16x8*)&lA[BI][aoff[QM][mi_][h_]];           \
    }                                                                         \
    bf16x8 bfr_[2][2];                                                        \
    _Pragma("unroll") for (int ni_ = 0; ni_ < 2; ++ni_)                       \
      _Pragma("unroll") for (int h_ = 0; h_ < 2; ++h_)                        \
        bfr_[ni_][h_] = *(const bf16x8*)&lB[BI][boff[QN][ni_][h_]];           \
    STAGE_STMT;                                                               \
    SBAR();                                                                   \
    __builtin_amdgcn_s_setprio(1);                                            \
    _Pragma("unroll") for (int mi_ = 0; mi_ < 4; ++mi_)                       \
      _Pragma("unroll") for (int ni_ = 0; ni_ < 2; ++ni_)                     \
        _Pragma("unroll") for (int h_ = 0; h_ < 2; ++h_)                      \
          acc[QM * 4 + mi_][QN * 2 + ni_] =                                   \
              __builtin_amdgcn_mfma_f32_16x16x32_bf16(                        \
                  af[mi_][h_], bfr_[ni_][h_],                                 \
                  acc[QM * 4 + mi_][QN * 2 + ni_], 0, 0, 0);                  \
    __builtin_amdgcn_s_setprio(0);                                            \
    WAIT_STMT;                                                                \
    SBAR();                                                                   \
  } while (0)

    // prologue: buf0 <- tile0 (A+B), buf1 A <- tile1. B1<-tile1 happens at
    // iter0 ph1. Wait A0+B0 complete (A1's 4 loads stay outstanding).
    STAGE_A(0, 0);
    STAGE_B(0, 0);
    STAGE_A(1, 64);
    WAITV4;
    SBAR();

    const int NIT = K >> 7;                 // 2 K-tiles per iteration
    for (int it = 0; it < NIT; ++it) {
        const int k1 = it * 128 + 64;       // buf1's tile (read ph5-8 this iter)
        int kn = it * 128 + 128;            // next buf0 tile
        if (kn > K - 64) kn = K - 64;       // last iter: harmless clamped loads
        int kn1 = it * 128 + 192;           // next buf1 tile
        if (kn1 > K - 64) kn1 = K - 64;

        PHASE(0, 0, 0, 1, STAGE_B(1, k1), (void)0);
        PHASE(0, 0, 1, 0, (void)0,        (void)0);
        PHASE(0, 1, 0, 1, (void)0,        (void)0);
        PHASE(0, 1, 1, 0, STAGE_A(0, kn), WAITV4);   // buf1 now ready
        PHASE(1, 0, 0, 1, STAGE_B(0, kn), (void)0);
        PHASE(1, 0, 1, 0, (void)0,        (void)0);
        PHASE(1, 1, 0, 1, (void)0,        (void)0);
        PHASE(1, 1, 1, 0, STAGE_A(1, kn1), WAITV4);  // next buf0 ready
    }

    asm volatile("s_waitcnt vmcnt(0)" ::: "memory");  // drain DMA before exit

    // D: row = quad*4+r, col = l16. Column range per block is uniform vs 2048.
    const bool isb_z = (tN >= 2048);
    u16* dst = isb_z ? Z : Xs;
#pragma unroll
    for (int mi = 0; mi < 8; ++mi) {
#pragma unroll
        for (int ni = 0; ni < 4; ++ni) {
            int col = tN + wc * 64 + ni * 16 + l16;
            float bv = bias[col];
            int ocol = isb_z ? (col - 2048) : col;
#pragma unroll
            for (int r = 0; r < 4; ++r) {
                int row = tM + wr * 128 + mi * 16 + quad * 4 + r;
                dst[(size_t)row * 2048 + ocol] = f2bf(acc[mi][ni][r] + bv);
            }
        }
    }
#undef PHASE
#undef STAGE_A
#undef STAGE_B
}

// ---------- narrow GEMM: BM=128, BN=64, BK=64, XOR-swizzled (round-6 form) ----------
// EPI 1 = dt: col<2048 -> min(softplus(v),1) bf16; 2048<=col<2080 -> raw dots bf16.
// EPI 2 = out: fp32 v + resid.
#define NBM 128
#define NBN 64
#define NBK 64

template <int EPI>
__global__ __launch_bounds__(256) void gemm_nw(const u16* __restrict__ A, int lda,
                                               const u16* __restrict__ W, int ldw,
                                               const float* __restrict__ bias,
                                               const float* __restrict__ resid,
                                               void* __restrict__ C, int ldc, int K,
                                               u16* __restrict__ dots) {
    __shared__ __align__(16) u16 lAB[(NBM + NBN) * NBK];  // 24 KB
    const int tid = threadIdx.x;
    const int wave = tid >> 6, lane = tid & 63;
    const int quad = lane >> 4, l16 = lane & 15;
    const int tM = blockIdx.x * NBM;
    const int tN = blockIdx.y * NBN;
    const int wr = wave >> 1, wc = wave & 1;

    const int rowin = tid >> 3;                    // 0..31
    const int r3 = rowin & 7;                      // swizzle key
    const int col8 = ((tid & 7) ^ r3) * 8;
    const u16* gptr[6];
    u16* ldst[6];
#pragma unroll
    for (int i = 0; i < 6; ++i) {
        int trow = i * 32 + rowin;
        const u16* src = (i < 4) ? (A + (size_t)(tM + trow) * lda)
                                 : (W + (size_t)(tN + (trow - NBM)) * ldw);
        gptr[i] = src + col8;
        ldst[i] = &lAB[(i * 32 + wave * 8) * NBK];
    }

    int a_off[2][4], b_off[2][2];
#pragma unroll
    for (int h = 0; h < 2; ++h) {
#pragma unroll
        for (int mi = 0; mi < 4; ++mi)
            a_off[h][mi] = (wr * 64 + mi * 16 + l16) * NBK +
                           (((h * 4 + quad) ^ (l16 & 7)) * 8);
#pragma unroll
        for (int ni = 0; ni < 2; ++ni)
            b_off[h][ni] = (NBM + wc * 32 + ni * 16 + l16) * NBK +
                           (((h * 4 + quad) ^ (l16 & 7)) * 8);
    }

    f32x4 acc[4][2] = {};

    for (int kt = 0; kt < K; kt += NBK) {
#pragma unroll
        for (int i = 0; i < 6; ++i) async16(gptr[i] + kt, ldst[i]);
        __syncthreads();
        bf16x8 af[2][4], bfr[2][2];
#pragma unroll
        for (int h = 0; h < 2; ++h) {
#pragma unroll
            for (int mi = 0; mi < 4; ++mi) af[h][mi] = *(const bf16x8*)&lAB[a_off[h][mi]];
#pragma unroll
            for (int ni = 0; ni < 2; ++ni) bfr[h][ni] = *(const bf16x8*)&lAB[b_off[h][ni]];
        }
#pragma unroll
        for (int h = 0; h < 2; ++h)
#pragma unroll
            for (int mi = 0; mi < 4; ++mi)
#pragma unroll
                for (int ni = 0; ni < 2; ++ni)
                    acc[mi][ni] = __builtin_amdgcn_mfma_f32_16x16x32_bf16(
                        af[h][mi], bfr[h][ni], acc[mi][ni], 0, 0, 0);
        __syncthreads();
    }

#pragma unroll
    for (int mi = 0; mi < 4; ++mi) {
#pragma unroll
        for (int ni = 0; ni < 2; ++ni) {
            int col = tN + wc * 32 + ni * 16 + l16;
            float bv = (EPI == 1 && col >= 2048) ? 0.f : bias[col];
#pragma unroll
            for (int r = 0; r < 4; ++r) {
                int row = tM + wr * 64 + mi * 16 + quad * 4 + r;
                float v = acc[mi][ni][r] + bv;
                if constexpr (EPI == 1) {
                    if (col < 2048) {
                        float sp = (v > 20.f) ? v : log1pf(__expf(v));
                        ((u16*)C)[(size_t)row * ldc + col] = f2bf(fminf(sp, 1.0f));
                    } else if (col < 2080) {
                        dots[(size_t)row * 32 + (col - 2048)] = f2bf(v);
                    }
                } else {
                    size_t idx = (size_t)row * ldc + col;
                    ((float*)C)[idx] = v + resid[idx];
                }
            }
        }
    }
}

// ---------- fused P + SSM + gate (split xs/z inputs) ----------
__global__ __launch_bounds__(256) void ssm_gate_kernel(const u16* __restrict__ dtb,
                                                       const u16* __restrict__ xsb,
                                                       const u16* __restrict__ zb,
                                                       const float* __restrict__ A,
                                                       const u16* __restrict__ dots,
                                                       const float* __restrict__ bB,
                                                       const float* __restrict__ bC,
                                                       u16* __restrict__ gated) {
    __shared__ float Pl[16];
    int t = blockIdx.x, tid = threadIdx.x;
    if (tid < 16) {
        float Bv = b2f(dots[(size_t)t * 32 + tid]) + bB[tid];
        float Cv = b2f(dots[(size_t)t * 32 + 16 + tid]) + bC[tid];
        Pl[tid] = Bv * Cv;
    }
    __syncthreads();
    size_t dbase = (size_t)t * DIM;
    int d0 = tid * 8;
    ushort4 dth[2], xsh[2], zh[2];
    dth[0] = *(const ushort4*)(dtb + dbase + d0);
    dth[1] = *(const ushort4*)(dtb + dbase + d0 + 4);
    xsh[0] = *(const ushort4*)(xsb + dbase + d0);
    xsh[1] = *(const ushort4*)(xsb + dbase + d0 + 4);
    zh[0]  = *(const ushort4*)(zb + dbase + d0);
    zh[1]  = *(const ushort4*)(zb + dbase + d0 + 4);
    float dtv[8], xsv[8], zv[8];
#pragma unroll
    for (int h = 0; h < 2; ++h) {
        const u16* dp = (const u16*)&dth[h];
        const u16* xp = (const u16*)&xsh[h];
        const u16* zp = (const u16*)&zh[h];
#pragma unroll
        for (int j = 0; j < 4; ++j) {
            dtv[h * 4 + j] = b2f(dp[j]);
            xsv[h * 4 + j] = b2f(xp[j]);
            zv[h * 4 + j]  = b2f(zp[j]);
        }
    }
    float s[8] = {};
#pragma unroll
    for (int n = 0; n < 16; ++n) {
        float4 a0 = *(const float4*)(A + n * DIM + d0);
        float4 a1 = *(const float4*)(A + n * DIM + d0 + 4);
        float pn = Pl[n];
        float av[8] = {a0.x, a0.y, a0.z, a0.w, a1.x, a1.y, a1.z, a1.w};
#pragma unroll
        for (int j = 0; j < 8; ++j) s[j] += pn * __expf(av[j] * dtv[j]);
    }
    ushort4 r0, r1;
    u16* rp0 = (u16*)&r0; u16* rp1 = (u16*)&r1;
#pragma unroll
    for (int j = 0; j < 8; ++j) {
        float y = s[j] * xsv[j];
        float sz = zv[j] * (1.0f / (1.0f + __expf(-zv[j])));
        u16 hv = f2bf(y * sz);
        if (j < 4) rp0[j] = hv; else rp1[j - 4] = hv;
    }
    *(ushort4*)(gated + dbase + d0) = r0;
    *(ushort4*)(gated + dbase + d0 + 4) = r1;
}

// ---------- launch ----------
// ws layout (84.15 MB peak):
//   R0 [0, 16.78M):       wb_in bf16 -> after gemm_wide: wb_out bf16 [0, 8.39M)
//   R1 [16.78M, 33.55M):  xnb bf16 -> wb_dt bf16 2112x2048 [16.78M, 25.43M)
//                         -> gated bf16 (after dt gemm, full R1)
//   R2 [33.55M, 50.33M):  xsb bf16 (T x D)
//   R3 [50.33M, 67.11M):  zb  bf16 (T x D)
//   R4 [67.11M, 83.89M):  dtb bf16 (T x D)
//   R5 [83.89M, 84.15M):  dots bf16 (T x 32)
extern "C" void kernel_launch(void* const* d_in, const int* in_sizes, int n_in,
                              void* d_out, int out_size, void* d_ws, size_t ws_size,
                              hipStream_t stream) {
    const float* x      = (const float*)d_in[0];
    const float* ln_g   = (const float*)d_in[1];
    const float* ln_b   = (const float*)d_in[2];
    const float* W_in   = (const float*)d_in[3];
    const float* b_in   = (const float*)d_in[4];
    const float* stateA = (const float*)d_in[5];
    const float* W_B    = (const float*)d_in[6];
    const float* b_B    = (const float*)d_in[7];
    const float* W_C    = (const float*)d_in[8];
    const float* b_C    = (const float*)d_in[9];
    const float* W_dt   = (const float*)d_in[10];
    const float* b_dt   = (const float*)d_in[11];
    const float* W_out  = (const float*)d_in[12];
    const float* b_out  = (const float*)d_in[13];

    char* ws = (char*)d_ws;
    u16*   wb_in  = (u16*)(ws);                     // R0
    u16*   wb_out = (u16*)(ws);                     // R0 reuse (8.4 MB)
    u16*   xnb    = (u16*)(ws + 16777216);          // R1
    u16*   wb_dt  = (u16*)(ws + 16777216);          // R1 reuse: 2112 x 2048
    u16*   gated  = (u16*)(ws + 16777216);          // R1 reuse: T x D
    u16*   xsb    = (u16*)(ws + 33554432);          // R2: T x D
    u16*   zb     = (u16*)(ws + 50331648);          // R3: T x D
    u16*   dtb    = (u16*)(ws + 67108864);          // R4: T x D
    u16*   dotsb  = (u16*)(ws + 83886080);          // R5: T x 32

    // 1. fused W_in cast + LN(x)
    castln_kernel<<<12288, 256, 0, stream>>>(W_in, wb_in, x, ln_g, ln_b, xnb);
    // 2. xz = xn @ W_in^T + b_in, split into xsb | zb   (256^2 8-phase, 256 blocks)
    gemm_wide<<<dim3(16, 16), 512, 0, stream>>>(xnb, wb_in, b_in, xsb, zb, 2048);
    // 3. cast W_dt -> wb_dt rows 0..2047, W_B -> 2048..2063, W_C -> 2064..2079,
    //    W_out -> wb_out (R0). Pad rows 2080..2111 hold poison; outputs discarded.
    cast4_kernel<<<8256, 256, 0, stream>>>(
        W_dt, wb_dt, 1048576,
        W_B,  wb_dt + (size_t)2048 * 2048, 8192,
        W_C,  wb_dt + (size_t)2064 * 2048, 8192,
        W_out, wb_out, 1048576);
    // 4. dt GEMM + BC dots: narrow tiles, N = 2112 (33 tiles), 1056 blocks
    gemm_nw<1><<<dim3(32, 33), 256, 0, stream>>>(xsb, 2048, wb_dt, 2048, b_dt,
                                                 nullptr, dtb, 2048, 2048, dotsb);
    // 5. fused P + SSM + gate (gated overwrites R1; wb_dt dead)
    ssm_gate_kernel<<<T_TOK, 256, 0, stream>>>(dtb, xsb, zb, stateA, dotsb,
                                               b_B, b_C, gated);
    // 6. out = gated @ W_out^T + b_out + x, narrow tiles, 1024 blocks
    gemm_nw<2><<<dim3(32, 32), 256, 0, stream>>>(gated, 2048, wb_out, 2048, b_out,
                                                 x, (float*)d_out, 2048, 2048, nullptr);
}